// Round 1
// baseline (950.131 us; speedup 1.0000x reference)
//
#include <hip/hip_runtime.h>

typedef unsigned short u16;
typedef __attribute__((ext_vector_type(8))) short bf16x8;
typedef __attribute__((ext_vector_type(8))) unsigned short u16x8;
typedef __attribute__((ext_vector_type(4))) unsigned short u16x4;
typedef __attribute__((ext_vector_type(4))) float f32x4;

__device__ inline float b2f(u16 u) {
    union { unsigned u32; float f; } x; x.u32 = ((unsigned)u) << 16; return x.f;
}
__device__ inline u16 f2b(float f) {
    union { float f; unsigned u; } x; x.f = f;
    unsigned r = x.u + 0x7fffu + ((x.u >> 16) & 1u);
    return (u16)(r >> 16);
}

#define GLOAD_LDS16(g, l) \
    __builtin_amdgcn_global_load_lds((const __attribute__((address_space(1))) void*)(const void*)(g), \
                                     (__attribute__((address_space(3))) void*)(void*)(l), 16, 0, 0)

// ---------------- LN1 + shift + window partition -> bf16 ----------------
// out row m = win*64+tok (windowed order), source token = natural order with roll.
__global__ __launch_bounds__(256)
void ln_win_kernel(const float* __restrict__ x, const float* __restrict__ g,
                   const float* __restrict__ b, u16* __restrict__ xw, int shift)
{
    int wid = blockIdx.x * 4 + (threadIdx.x >> 6);
    int lane = threadIdx.x & 63;
    int win = wid >> 6, tok = wid & 63;
    int bb = win >> 6, wib = win & 63;
    int h = (((wib >> 3) << 3) + (tok >> 3) + shift) & 63;
    int w = (((wib & 7) << 3) + (tok & 7) + shift) & 63;
    size_t src = ((size_t)bb * 4096 + h * 64 + w) * 256;
    float4 v = ((const float4*)(x + src))[lane];
    float s = v.x + v.y + v.z + v.w;
    float s2 = v.x*v.x + v.y*v.y + v.z*v.z + v.w*v.w;
    for (int k = 32; k > 0; k >>= 1) { s += __shfl_xor(s, k); s2 += __shfl_xor(s2, k); }
    float mean = s * (1.f/256.f);
    float var  = s2 * (1.f/256.f) - mean*mean;
    float rs = rsqrtf(var + 1e-5f);
    int c = lane * 4;
    u16x4 o;
    o[0] = f2b((v.x - mean) * rs * g[c+0] + b[c+0]);
    o[1] = f2b((v.y - mean) * rs * g[c+1] + b[c+1]);
    o[2] = f2b((v.z - mean) * rs * g[c+2] + b[c+2]);
    o[3] = f2b((v.w - mean) * rs * g[c+3] + b[c+3]);
    *(u16x4*)(xw + (size_t)wid * 256 + c) = o;
}

// ---------------- fused LN2(1e-5) then LN3(1e-6) -> bf16 (natural order) ---
__global__ __launch_bounds__(256)
void ln2_kernel(const float* __restrict__ xin,
                const float* __restrict__ g1, const float* __restrict__ b1,
                const float* __restrict__ g2, const float* __restrict__ b2,
                u16* __restrict__ out)
{
    int wid = blockIdx.x * 4 + (threadIdx.x >> 6);
    int lane = threadIdx.x & 63;
    float4 v = ((const float4*)(xin + (size_t)wid * 256))[lane];
    float s = v.x + v.y + v.z + v.w;
    float s2 = v.x*v.x + v.y*v.y + v.z*v.z + v.w*v.w;
    for (int k = 32; k > 0; k >>= 1) { s += __shfl_xor(s, k); s2 += __shfl_xor(s2, k); }
    float mean = s * (1.f/256.f);
    float var  = s2 * (1.f/256.f) - mean*mean;
    float rs = rsqrtf(var + 1e-5f);
    int c = lane * 4;
    float y0 = (v.x - mean) * rs * g1[c+0] + b1[c+0];
    float y1 = (v.y - mean) * rs * g1[c+1] + b1[c+1];
    float y2 = (v.z - mean) * rs * g1[c+2] + b1[c+2];
    float y3 = (v.w - mean) * rs * g1[c+3] + b1[c+3];
    float t = y0 + y1 + y2 + y3;
    float t2 = y0*y0 + y1*y1 + y2*y2 + y3*y3;
    for (int k = 32; k > 0; k >>= 1) { t += __shfl_xor(t, k); t2 += __shfl_xor(t2, k); }
    float m2 = t * (1.f/256.f);
    float v2 = t2 * (1.f/256.f) - m2*m2;
    float rs2 = rsqrtf(v2 + 1e-6f);
    u16x4 o;
    o[0] = f2b((y0 - m2) * rs2 * g2[c+0] + b2[c+0]);
    o[1] = f2b((y1 - m2) * rs2 * g2[c+1] + b2[c+1]);
    o[2] = f2b((y2 - m2) * rs2 * g2[c+2] + b2[c+2]);
    o[3] = f2b((y3 - m2) * rs2 * g2[c+3] + b2[c+3]);
    *(u16x4*)(out + (size_t)wid * 256 + c) = o;
}

// ---------------- weight transpose f32[K][N] -> bf16 Wt[N][K] --------------
__global__ __launch_bounds__(256)
void transpose_w(const float* __restrict__ W, u16* __restrict__ Wt, int K, int N)
{
    __shared__ float t[32][33];
    int nb = blockIdx.x * 32, kb = blockIdx.y * 32;
    int tx = threadIdx.x & 31, ty = threadIdx.x >> 5;
    #pragma unroll
    for (int r = 0; r < 32; r += 8)
        t[ty + r][tx] = W[(size_t)(kb + ty + r) * N + nb + tx];
    __syncthreads();
    #pragma unroll
    for (int r = 0; r < 32; r += 8)
        Wt[(size_t)(nb + ty + r) * K + kb + tx] = f2b(t[tx][ty + r]);
}

// ---------------- 128x128 tile bf16 MFMA GEMM, templated epilogue ----------
// EPI 0: bf16 store (C = A*Bt^T + bias)
// EPI 1: gelu(exact) -> bf16 store
// EPI 2: f32 store with window-reverse row remap + residual add
// EPI 3: f32 store + residual add (identity rows)
template<int EPI>
__global__ __launch_bounds__(256)
void gemm_bf16(const u16* __restrict__ A, const u16* __restrict__ Bt,
               const float* __restrict__ bias, void* __restrict__ out,
               const float* __restrict__ resid, int M, int N, int K, int shift)
{
    __shared__ u16 As[128 * 32];
    __shared__ u16 Bs[128 * 32];
    const int tid = threadIdx.x;
    const int lane = tid & 63, wv = tid >> 6;
    const int bm = blockIdx.y, bn = blockIdx.x;
    const int wr = wv >> 1, wc = wv & 1;
    f32x4 acc[4][4] = {};
    const int arow = wv * 16 + (lane >> 2);
    const int acol = (lane & 3) * 8;
    const u16* gA = A + (size_t)(bm * 128 + arow) * K + acol;
    const u16* gB = Bt + (size_t)(bn * 128 + arow) * K + acol;
    const int nk = K >> 5;
    for (int kt = 0; kt < nk; ++kt) {
        __syncthreads();
        GLOAD_LDS16(gA,          As + wv * 512);
        GLOAD_LDS16(gA + 64 * K, As + 2048 + wv * 512);
        GLOAD_LDS16(gB,          Bs + wv * 512);
        GLOAD_LDS16(gB + 64 * K, Bs + 2048 + wv * 512);
        gA += 32; gB += 32;
        __syncthreads();
        const int g = lane >> 4, r = lane & 15;
        bf16x8 af[4], bf[4];
        #pragma unroll
        for (int i = 0; i < 4; ++i)
            af[i] = *(const bf16x8*)(As + (wr * 64 + i * 16 + r) * 32 + g * 8);
        #pragma unroll
        for (int i = 0; i < 4; ++i)
            bf[i] = *(const bf16x8*)(Bs + (wc * 64 + i * 16 + r) * 32 + g * 8);
        #pragma unroll
        for (int i = 0; i < 4; ++i)
            #pragma unroll
            for (int j = 0; j < 4; ++j)
                acc[i][j] = __builtin_amdgcn_mfma_f32_16x16x32_bf16(af[i], bf[j], acc[i][j], 0, 0, 0);
    }
    const int r4 = (lane >> 4) * 4;
    const int cn = lane & 15;
    #pragma unroll
    for (int i = 0; i < 4; ++i) {
        #pragma unroll
        for (int rr = 0; rr < 4; ++rr) {
            int row = bm * 128 + wr * 64 + i * 16 + r4 + rr;
            size_t orow;
            if (EPI == 2) {
                int win = row >> 6, tok = row & 63;
                int bb = win >> 6, wib = win & 63;
                int h = (((wib >> 3) << 3) + (tok >> 3) + shift) & 63;
                int w = (((wib & 7) << 3) + (tok & 7) + shift) & 63;
                orow = (size_t)bb * 4096 + h * 64 + w;
            } else {
                orow = (size_t)row;
            }
            #pragma unroll
            for (int j = 0; j < 4; ++j) {
                int col = bn * 128 + wc * 64 + j * 16 + cn;
                float v = acc[i][j][rr] + bias[col];
                if (EPI == 0) {
                    ((u16*)out)[(size_t)row * N + col] = f2b(v);
                } else if (EPI == 1) {
                    float ge = 0.5f * v * (1.f + erff(v * 0.70710678118654752f));
                    ((u16*)out)[(size_t)row * N + col] = f2b(ge);
                } else {
                    ((float*)out)[orow * N + col] = resid[orow * N + col] + v;
                }
            }
        }
    }
}

// ---------------- attention: one wave per (window, head) -------------------
template<int SHIFTED>
__global__ __launch_bounds__(64)
void attn_kernel(const u16* __restrict__ qkv, const float* __restrict__ rpb,
                 u16* __restrict__ out)
{
    __shared__ float ks[64][33];
    __shared__ float vs[64][33];
    __shared__ float bb[225];
    const int t = threadIdx.x;
    const int win = blockIdx.x >> 3;
    const int head = blockIdx.x & 7;
    for (int i = t; i < 225; i += 64) bb[i] = rpb[i * 8 + head];
    const size_t rowb = (size_t)(win * 64 + t) * 768;
    const u16* qp = qkv + rowb + head * 32;
    const u16* kp = qp + 256;
    const u16* vp = qp + 512;
    float q[32];
    #pragma unroll
    for (int d0 = 0; d0 < 32; d0 += 8) {
        u16x8 kk = *(const u16x8*)(kp + d0);
        u16x8 vv = *(const u16x8*)(vp + d0);
        u16x8 qq = *(const u16x8*)(qp + d0);
        #pragma unroll
        for (int e = 0; e < 8; ++e) {
            ks[t][d0 + e] = b2f(kk[e]);
            vs[t][d0 + e] = b2f(vv[e]);
            q[d0 + e] = b2f(qq[e]);
        }
    }
    __syncthreads();
    const int th = t >> 3, tw = t & 7;
    const int wib = win & 63, wh = wib >> 3, ww = wib & 7;
    int regq = 0;
    if (SHIFTED) {
        int rh = (wh < 7) ? 0 : ((th < 4) ? 1 : 2);
        int rw = (ww < 7) ? 0 : ((tw < 4) ? 1 : 2);
        regq = rh * 3 + rw;
    }
    float s[64];
    float mx = -1e30f;
    #pragma unroll
    for (int j = 0; j < 64; ++j) {
        float a = 0.f;
        #pragma unroll
        for (int d = 0; d < 32; ++d) a += q[d] * ks[j][d];
        a *= 0.17677669529663687f;
        const int jh = j >> 3, jw = j & 7;
        a += bb[(th - jh + 7) * 15 + (tw - jw + 7)];
        if (SHIFTED) {
            int rh = (wh < 7) ? 0 : ((jh < 4) ? 1 : 2);
            int rw = (ww < 7) ? 0 : ((jw < 4) ? 1 : 2);
            if (rh * 3 + rw != regq) a -= 100.f;
        }
        s[j] = a;
        mx = fmaxf(mx, a);
    }
    float sum = 0.f;
    #pragma unroll
    for (int j = 0; j < 64; ++j) { float p = __expf(s[j] - mx); s[j] = p; sum += p; }
    const float inv = 1.f / sum;
    u16* op = out + (size_t)(win * 64 + t) * 256 + head * 32;
    #pragma unroll
    for (int d0 = 0; d0 < 32; d0 += 8) {
        u16x8 o;
        #pragma unroll
        for (int e = 0; e < 8; ++e) {
            float acc = 0.f;
            #pragma unroll
            for (int j = 0; j < 64; ++j) acc += s[j] * vs[j][d0 + e];
            o[e] = f2b(acc * inv);
        }
        *(u16x8*)(op + d0) = o;
    }
}

// ---------------------------------------------------------------------------
extern "C" void kernel_launch(void* const* d_in, const int* in_sizes, int n_in,
                              void* d_out, int out_size, void* d_ws, size_t ws_size,
                              hipStream_t stream)
{
    (void)in_sizes; (void)n_in; (void)out_size; (void)ws_size;
    const float* x = (const float*)d_in[0];
    char* ws = (char*)d_ws;
    size_t off = 0;
    auto alloc = [&](size_t bytes) { void* p = ws + off; off += (bytes + 255) & ~(size_t)255; return p; };

    u16 *wtq[2], *wto[2], *wt1[2], *wt2[2];
    for (int i = 0; i < 2; ++i) {
        wtq[i] = (u16*)alloc((size_t)768 * 256 * 2);
        wto[i] = (u16*)alloc((size_t)256 * 256 * 2);
        wt1[i] = (u16*)alloc((size_t)1024 * 256 * 2);
        wt2[i] = (u16*)alloc((size_t)256 * 1024 * 2);
    }
    u16*  xw  = (u16*)alloc((size_t)65536 * 256 * 2);   // LN out / attn out / LN2 out
    u16*  big = (u16*)alloc((size_t)65536 * 1024 * 2);  // qkv (768) / mlp hidden (1024)
    float* x1 = (float*)alloc((size_t)65536 * 256 * 4); // post-attention residual stream
    float* outp = (float*)d_out;

    for (int blk = 0; blk < 2; ++blk) {
        const float* const* P = (const float* const*)(d_in + 1 + blk * 15);
        transpose_w<<<dim3(768 / 32, 256 / 32), 256, 0, stream>>>(P[2], wtq[blk], 256, 768);
        transpose_w<<<dim3(256 / 32, 256 / 32), 256, 0, stream>>>(P[5], wto[blk], 256, 256);
        transpose_w<<<dim3(1024 / 32, 256 / 32), 256, 0, stream>>>(P[11], wt1[blk], 256, 1024);
        transpose_w<<<dim3(256 / 32, 1024 / 32), 256, 0, stream>>>(P[13], wt2[blk], 1024, 256);
    }

    for (int blk = 0; blk < 2; ++blk) {
        const float* const* P = (const float* const*)(d_in + 1 + blk * 15);
        // P: 0 n1g, 1 n1b, 2 qkv_w, 3 qkv_b, 4 rpb, 5 out_w, 6 out_b,
        //    7 n2g, 8 n2b, 9 lng, 10 lnb, 11 w1, 12 b1, 13 w2, 14 b2
        const int sh = blk ? 4 : 0;
        const float* xin = blk ? outp : x;

        ln_win_kernel<<<16384, 256, 0, stream>>>(xin, P[0], P[1], xw, sh);
        gemm_bf16<0><<<dim3(6, 512), 256, 0, stream>>>(xw, wtq[blk], P[3], big, nullptr, 65536, 768, 256, 0);
        if (blk) attn_kernel<1><<<8192, 64, 0, stream>>>(big, P[4], xw);
        else     attn_kernel<0><<<8192, 64, 0, stream>>>(big, P[4], xw);
        gemm_bf16<2><<<dim3(2, 512), 256, 0, stream>>>(xw, wto[blk], P[6], x1, xin, 65536, 256, 256, sh);
        ln2_kernel<<<16384, 256, 0, stream>>>(x1, P[7], P[8], P[9], P[10], xw);
        gemm_bf16<1><<<dim3(8, 512), 256, 0, stream>>>(xw, wt1[blk], P[12], big, nullptr, 65536, 1024, 256, 0);
        gemm_bf16<3><<<dim3(2, 512), 256, 0, stream>>>(big, wt2[blk], P[14], outp, x1, 65536, 256, 1024, 0);
    }
}

// Round 2
// 748.791 us; speedup vs baseline: 1.2689x; 1.2689x over previous
//
#include <hip/hip_runtime.h>

typedef unsigned short u16;
typedef __attribute__((ext_vector_type(8))) short bf16x8;
typedef __attribute__((ext_vector_type(8))) unsigned short u16x8;
typedef __attribute__((ext_vector_type(4))) unsigned short u16x4;
typedef __attribute__((ext_vector_type(4))) float f32x4;

__device__ inline float b2f(u16 u) {
    union { unsigned u32; float f; } x; x.u32 = ((unsigned)u) << 16; return x.f;
}
__device__ inline u16 f2b(float f) {
    union { float f; unsigned u; } x; x.f = f;
    unsigned r = x.u + 0x7fffu + ((x.u >> 16) & 1u);
    return (u16)(r >> 16);
}

#define GLOAD_LDS16(g, l) \
    __builtin_amdgcn_global_load_lds((const __attribute__((address_space(1))) void*)(const void*)(g), \
                                     (__attribute__((address_space(3))) void*)(void*)(l), 16, 0, 0)

// ---------------- LN1 + shift + window partition -> bf16 ----------------
__global__ __launch_bounds__(256)
void ln_win_kernel(const float* __restrict__ x, const float* __restrict__ g,
                   const float* __restrict__ b, u16* __restrict__ xw, int shift)
{
    int wid = blockIdx.x * 4 + (threadIdx.x >> 6);
    int lane = threadIdx.x & 63;
    int win = wid >> 6, tok = wid & 63;
    int bb = win >> 6, wib = win & 63;
    int h = (((wib >> 3) << 3) + (tok >> 3) + shift) & 63;
    int w = (((wib & 7) << 3) + (tok & 7) + shift) & 63;
    size_t src = ((size_t)bb * 4096 + h * 64 + w) * 256;
    float4 v = ((const float4*)(x + src))[lane];
    float s = v.x + v.y + v.z + v.w;
    float s2 = v.x*v.x + v.y*v.y + v.z*v.z + v.w*v.w;
    for (int k = 32; k > 0; k >>= 1) { s += __shfl_xor(s, k); s2 += __shfl_xor(s2, k); }
    float mean = s * (1.f/256.f);
    float var  = s2 * (1.f/256.f) - mean*mean;
    float rs = rsqrtf(var + 1e-5f);
    int c = lane * 4;
    u16x4 o;
    o[0] = f2b((v.x - mean) * rs * g[c+0] + b[c+0]);
    o[1] = f2b((v.y - mean) * rs * g[c+1] + b[c+1]);
    o[2] = f2b((v.z - mean) * rs * g[c+2] + b[c+2]);
    o[3] = f2b((v.w - mean) * rs * g[c+3] + b[c+3]);
    *(u16x4*)(xw + (size_t)wid * 256 + c) = o;
}

// ---------------- fused LN2(1e-5) then LN3(1e-6) -> bf16 -------------------
__global__ __launch_bounds__(256)
void ln2_kernel(const float* __restrict__ xin,
                const float* __restrict__ g1, const float* __restrict__ b1,
                const float* __restrict__ g2, const float* __restrict__ b2,
                u16* __restrict__ out)
{
    int wid = blockIdx.x * 4 + (threadIdx.x >> 6);
    int lane = threadIdx.x & 63;
    float4 v = ((const float4*)(xin + (size_t)wid * 256))[lane];
    float s = v.x + v.y + v.z + v.w;
    float s2 = v.x*v.x + v.y*v.y + v.z*v.z + v.w*v.w;
    for (int k = 32; k > 0; k >>= 1) { s += __shfl_xor(s, k); s2 += __shfl_xor(s2, k); }
    float mean = s * (1.f/256.f);
    float var  = s2 * (1.f/256.f) - mean*mean;
    float rs = rsqrtf(var + 1e-5f);
    int c = lane * 4;
    float y0 = (v.x - mean) * rs * g1[c+0] + b1[c+0];
    float y1 = (v.y - mean) * rs * g1[c+1] + b1[c+1];
    float y2 = (v.z - mean) * rs * g1[c+2] + b1[c+2];
    float y3 = (v.w - mean) * rs * g1[c+3] + b1[c+3];
    float t = y0 + y1 + y2 + y3;
    float t2 = y0*y0 + y1*y1 + y2*y2 + y3*y3;
    for (int k = 32; k > 0; k >>= 1) { t += __shfl_xor(t, k); t2 += __shfl_xor(t2, k); }
    float m2 = t * (1.f/256.f);
    float v2 = t2 * (1.f/256.f) - m2*m2;
    float rs2 = rsqrtf(v2 + 1e-6f);
    u16x4 o;
    o[0] = f2b((y0 - m2) * rs2 * g2[c+0] + b2[c+0]);
    o[1] = f2b((y1 - m2) * rs2 * g2[c+1] + b2[c+1]);
    o[2] = f2b((y2 - m2) * rs2 * g2[c+2] + b2[c+2]);
    o[3] = f2b((y3 - m2) * rs2 * g2[c+3] + b2[c+3]);
    *(u16x4*)(out + (size_t)wid * 256 + c) = o;
}

// ---------------- weight transpose f32[K][N] -> bf16 Wt[N][K] --------------
__global__ __launch_bounds__(256)
void transpose_w(const float* __restrict__ W, u16* __restrict__ Wt, int K, int N)
{
    __shared__ float t[32][33];
    int nb = blockIdx.x * 32, kb = blockIdx.y * 32;
    int tx = threadIdx.x & 31, ty = threadIdx.x >> 5;
    #pragma unroll
    for (int r = 0; r < 32; r += 8)
        t[ty + r][tx] = W[(size_t)(kb + ty + r) * N + nb + tx];
    __syncthreads();
    #pragma unroll
    for (int r = 0; r < 32; r += 8)
        Wt[(size_t)(nb + ty + r) * K + kb + tx] = f2b(t[tx][ty + r]);
}

// ---------------- bias(+mask) table: bmT[cls][h][k][q] * log2e -------------
__global__ __launch_bounds__(256)
void build_bias(const float* __restrict__ rpb, float* __restrict__ bmT)
{
    int idx = blockIdx.x * 256 + threadIdx.x;      // 4*8*64*64 = 131072
    int q = idx & 63, k = (idx >> 6) & 63, h = (idx >> 12) & 7, cls = idx >> 15;
    int qh = q >> 3, qw = q & 7, kh = k >> 3, kw = k & 7;
    float v = rpb[((qh - kh + 7) * 15 + (qw - kw + 7)) * 8 + h];
    int ch = cls >> 1, cw = cls & 1;
    int rq = (ch ? (qh < 4 ? 1 : 2) : 0) * 3 + (cw ? (qw < 4 ? 1 : 2) : 0);
    int rk = (ch ? (kh < 4 ? 1 : 2) : 0) * 3 + (cw ? (kw < 4 ? 1 : 2) : 0);
    if (rq != rk) v -= 100.f;
    bmT[idx] = v * 1.4426950408889634f;
}

// ---------------- 128x128 tile bf16 MFMA GEMM, templated epilogue ----------
template<int EPI>
__global__ __launch_bounds__(256)
void gemm_bf16(const u16* __restrict__ A, const u16* __restrict__ Bt,
               const float* __restrict__ bias, void* __restrict__ out,
               const float* __restrict__ resid, int M, int N, int K, int shift)
{
    __shared__ u16 As[128 * 32];
    __shared__ u16 Bs[128 * 32];
    const int tid = threadIdx.x;
    const int lane = tid & 63, wv = tid >> 6;
    const int bm = blockIdx.y, bn = blockIdx.x;
    const int wr = wv >> 1, wc = wv & 1;
    f32x4 acc[4][4] = {};
    const int arow = wv * 16 + (lane >> 2);
    const int acol = (lane & 3) * 8;
    const u16* gA = A + (size_t)(bm * 128 + arow) * K + acol;
    const u16* gB = Bt + (size_t)(bn * 128 + arow) * K + acol;
    const int nk = K >> 5;
    for (int kt = 0; kt < nk; ++kt) {
        __syncthreads();
        GLOAD_LDS16(gA,          As + wv * 512);
        GLOAD_LDS16(gA + 64 * K, As + 2048 + wv * 512);
        GLOAD_LDS16(gB,          Bs + wv * 512);
        GLOAD_LDS16(gB + 64 * K, Bs + 2048 + wv * 512);
        gA += 32; gB += 32;
        __syncthreads();
        const int g = lane >> 4, r = lane & 15;
        bf16x8 af[4], bf[4];
        #pragma unroll
        for (int i = 0; i < 4; ++i)
            af[i] = *(const bf16x8*)(As + (wr * 64 + i * 16 + r) * 32 + g * 8);
        #pragma unroll
        for (int i = 0; i < 4; ++i)
            bf[i] = *(const bf16x8*)(Bs + (wc * 64 + i * 16 + r) * 32 + g * 8);
        #pragma unroll
        for (int i = 0; i < 4; ++i)
            #pragma unroll
            for (int j = 0; j < 4; ++j)
                acc[i][j] = __builtin_amdgcn_mfma_f32_16x16x32_bf16(af[i], bf[j], acc[i][j], 0, 0, 0);
    }
    const int r4 = (lane >> 4) * 4;
    const int cn = lane & 15;
    #pragma unroll
    for (int i = 0; i < 4; ++i) {
        #pragma unroll
        for (int rr = 0; rr < 4; ++rr) {
            int row = bm * 128 + wr * 64 + i * 16 + r4 + rr;
            size_t orow;
            if (EPI == 2) {
                int win = row >> 6, tok = row & 63;
                int bb = win >> 6, wib = win & 63;
                int h = (((wib >> 3) << 3) + (tok >> 3) + shift) & 63;
                int w = (((wib & 7) << 3) + (tok & 7) + shift) & 63;
                orow = (size_t)bb * 4096 + h * 64 + w;
            } else {
                orow = (size_t)row;
            }
            #pragma unroll
            for (int j = 0; j < 4; ++j) {
                int col = bn * 128 + wc * 64 + j * 16 + cn;
                float v = acc[i][j][rr] + bias[col];
                if (EPI == 0) {
                    ((u16*)out)[(size_t)row * N + col] = f2b(v);
                } else if (EPI == 1) {
                    float ge = 0.5f * v * (1.f + erff(v * 0.70710678118654752f));
                    ((u16*)out)[(size_t)row * N + col] = f2b(ge);
                } else {
                    ((float*)out)[orow * N + col] = resid[orow * N + col] + v;
                }
            }
        }
    }
}

// ---------------- MFMA attention: one block per window, wave = 2 heads -----
// S^T = mfma(K, Q): lane holds S^T[k = i*16+g*4+rr][q = j*16+r].
// Softmax over k: lane-local (16 vals) + shfl_xor(16,32). inv_sum lane-local.
// P packed to LDS [q][72] via u16x4 (8B) writes; Vt staged [d][72].
// PV = mfma(P, Vt) -> out[q][d].
template<int SHIFTED>
__global__ __launch_bounds__(256)
void attn_mfma(const u16* __restrict__ qkv, const float* __restrict__ bmT,
               u16* __restrict__ out)
{
    __shared__ u16 pbuf[4][64 * 72];
    __shared__ u16 vbuf[4][32 * 72];
    const int tid = threadIdx.x, lane = tid & 63, wv = tid >> 6;
    const int g = lane >> 4, r = lane & 15;
    const int win = blockIdx.x;
    u16* P  = pbuf[wv];
    u16* Vt = vbuf[wv];
    const u16* base = qkv + (size_t)win * 64 * 768;
    int cls = 0;
    if (SHIFTED) {
        int wib = win & 63;
        cls = (((wib >> 3) == 7) ? 2 : 0) + (((wib & 7) == 7) ? 1 : 0);
    }
    const float sc = 0.17677669529663687f * 1.4426950408889634f;

    for (int hh = 0; hh < 2; ++hh) {
        const int h = wv * 2 + hh;
        const float* bmh = bmT + ((size_t)cls * 8 + h) * 4096;
        bf16x8 kf[4], qf[4];
        #pragma unroll
        for (int i = 0; i < 4; ++i) {
            kf[i] = *(const bf16x8*)(base + (size_t)(i * 16 + r) * 768 + 256 + h * 32 + g * 8);
            qf[i] = *(const bf16x8*)(base + (size_t)(i * 16 + r) * 768 +       h * 32 + g * 8);
        }
        // stage V transposed: Vt[d][k], lane handles k = lane
        #pragma unroll
        for (int d0 = 0; d0 < 32; d0 += 8) {
            u16x8 vv = *(const u16x8*)(base + (size_t)lane * 768 + 512 + h * 32 + d0);
            #pragma unroll
            for (int e = 0; e < 8; ++e) Vt[(d0 + e) * 72 + lane] = vv[e];
        }
        f32x4 acc[4][4] = {};
        #pragma unroll
        for (int i = 0; i < 4; ++i)
            #pragma unroll
            for (int j = 0; j < 4; ++j)
                acc[i][j] = __builtin_amdgcn_mfma_f32_16x16x32_bf16(kf[i], qf[j], acc[i][j], 0, 0, 0);
        // scale + bias(+mask), all pre-multiplied by log2e
        #pragma unroll
        for (int i = 0; i < 4; ++i) {
            const int kb = (i * 16 + g * 4) * 64;
            #pragma unroll
            for (int j = 0; j < 4; ++j) {
                const int qq = j * 16 + r;
                #pragma unroll
                for (int rr = 0; rr < 4; ++rr)
                    acc[i][j][rr] = acc[i][j][rr] * sc + bmh[kb + rr * 64 + qq];
            }
        }
        // softmax per column q (= per j), k spread over (i,rr) local + g lanes
        float inv_[4];
        #pragma unroll
        for (int j = 0; j < 4; ++j) {
            float m = acc[0][j][0];
            #pragma unroll
            for (int i = 0; i < 4; ++i)
                #pragma unroll
                for (int rr = 0; rr < 4; ++rr) m = fmaxf(m, acc[i][j][rr]);
            m = fmaxf(m, __shfl_xor(m, 16));
            m = fmaxf(m, __shfl_xor(m, 32));
            float s = 0.f;
            #pragma unroll
            for (int i = 0; i < 4; ++i)
                #pragma unroll
                for (int rr = 0; rr < 4; ++rr) {
                    float p = exp2f(acc[i][j][rr] - m);
                    acc[i][j][rr] = p; s += p;
                }
            s += __shfl_xor(s, 16);
            s += __shfl_xor(s, 32);
            inv_[j] = 1.f / s;
        }
        // pack P (normalized) to LDS: rows q, k contiguous; 4 k per 8B write
        #pragma unroll
        for (int j = 0; j < 4; ++j) {
            const float iv = inv_[j];
            #pragma unroll
            for (int i = 0; i < 4; ++i) {
                u16x4 w;
                #pragma unroll
                for (int rr = 0; rr < 4; ++rr) w[rr] = f2b(acc[i][j][rr] * iv);
                *(u16x4*)(P + (j * 16 + r) * 72 + i * 16 + g * 4) = w;
            }
        }
        // PV
        f32x4 o[4][2] = {};
        #pragma unroll
        for (int ks = 0; ks < 2; ++ks) {
            bf16x8 pa[4], vb[2];
            #pragma unroll
            for (int i = 0; i < 4; ++i)
                pa[i] = *(const bf16x8*)(P + (i * 16 + r) * 72 + ks * 32 + g * 8);
            #pragma unroll
            for (int j = 0; j < 2; ++j)
                vb[j] = *(const bf16x8*)(Vt + (j * 16 + r) * 72 + ks * 32 + g * 8);
            #pragma unroll
            for (int i = 0; i < 4; ++i)
                #pragma unroll
                for (int j = 0; j < 2; ++j)
                    o[i][j] = __builtin_amdgcn_mfma_f32_16x16x32_bf16(pa[i], vb[j], o[i][j], 0, 0, 0);
        }
        u16* op = out + (size_t)win * 64 * 256 + h * 32;
        #pragma unroll
        for (int i = 0; i < 4; ++i)
            #pragma unroll
            for (int j = 0; j < 2; ++j)
                #pragma unroll
                for (int rr = 0; rr < 4; ++rr)
                    op[(size_t)(i * 16 + g * 4 + rr) * 256 + j * 16 + r] = f2b(o[i][j][rr]);
    }
}

// ---------------------------------------------------------------------------
extern "C" void kernel_launch(void* const* d_in, const int* in_sizes, int n_in,
                              void* d_out, int out_size, void* d_ws, size_t ws_size,
                              hipStream_t stream)
{
    (void)in_sizes; (void)n_in; (void)out_size; (void)ws_size;
    const float* x = (const float*)d_in[0];
    char* ws = (char*)d_ws;
    size_t off = 0;
    auto alloc = [&](size_t bytes) { void* p = ws + off; off += (bytes + 255) & ~(size_t)255; return p; };

    u16 *wtq[2], *wto[2], *wt1[2], *wt2[2];
    float* bmT[2];
    for (int i = 0; i < 2; ++i) {
        wtq[i] = (u16*)alloc((size_t)768 * 256 * 2);
        wto[i] = (u16*)alloc((size_t)256 * 256 * 2);
        wt1[i] = (u16*)alloc((size_t)1024 * 256 * 2);
        wt2[i] = (u16*)alloc((size_t)256 * 1024 * 2);
        bmT[i] = (float*)alloc((size_t)4 * 8 * 64 * 64 * 4);
    }
    u16*  xw  = (u16*)alloc((size_t)65536 * 256 * 2);
    u16*  big = (u16*)alloc((size_t)65536 * 1024 * 2);
    float* x1 = (float*)alloc((size_t)65536 * 256 * 4);
    float* outp = (float*)d_out;

    for (int blk = 0; blk < 2; ++blk) {
        const float* const* P = (const float* const*)(d_in + 1 + blk * 15);
        transpose_w<<<dim3(768 / 32, 256 / 32), 256, 0, stream>>>(P[2], wtq[blk], 256, 768);
        transpose_w<<<dim3(256 / 32, 256 / 32), 256, 0, stream>>>(P[5], wto[blk], 256, 256);
        transpose_w<<<dim3(1024 / 32, 256 / 32), 256, 0, stream>>>(P[11], wt1[blk], 256, 1024);
        transpose_w<<<dim3(256 / 32, 1024 / 32), 256, 0, stream>>>(P[13], wt2[blk], 1024, 256);
        build_bias<<<512, 256, 0, stream>>>(P[4], bmT[blk]);
    }

    for (int blk = 0; blk < 2; ++blk) {
        const float* const* P = (const float* const*)(d_in + 1 + blk * 15);
        const int sh = blk ? 4 : 0;
        const float* xin = blk ? outp : x;

        ln_win_kernel<<<16384, 256, 0, stream>>>(xin, P[0], P[1], xw, sh);
        gemm_bf16<0><<<dim3(6, 512), 256, 0, stream>>>(xw, wtq[blk], P[3], big, nullptr, 65536, 768, 256, 0);
        if (blk) attn_mfma<1><<<1024, 256, 0, stream>>>(big, bmT[blk], xw);
        else     attn_mfma<0><<<1024, 256, 0, stream>>>(big, bmT[blk], xw);
        gemm_bf16<2><<<dim3(2, 512), 256, 0, stream>>>(xw, wto[blk], P[6], x1, xin, 65536, 256, 256, sh);
        ln2_kernel<<<16384, 256, 0, stream>>>(x1, P[7], P[8], P[9], P[10], xw);
        gemm_bf16<1><<<dim3(8, 512), 256, 0, stream>>>(xw, wt1[blk], P[12], big, nullptr, 65536, 1024, 256, 0);
        gemm_bf16<3><<<dim3(2, 512), 256, 0, stream>>>(big, wt2[blk], P[14], outp, x1, 65536, 256, 1024, 0);
    }
}